// Round 5
// baseline (164.402 us; speedup 1.0000x reference)
//
#include <hip/hip_runtime.h>
#include <hip/hip_bf16.h>
#include <math.h>

#define D_MODEL 512
#define NH 8
#define DH 64
#define LA 256
#define LB 256
#define LC 32
#define BATCH 4
#define KC_TOT (LB * LC)   // 8192
#define QT 32              // q rows per block
#define NT 512             // kc per tile iteration (64 per wave x 8 waves)
#define NWAVES 8

typedef float f32x4 __attribute__((ext_vector_type(4)));
typedef _Float16 f16x8 __attribute__((ext_vector_type(8)));
typedef _Float16 f16x4 __attribute__((ext_vector_type(4)));

#if __has_builtin(__builtin_amdgcn_exp2f)
#define EXP2(x) __builtin_amdgcn_exp2f(x)
#else
#define EXP2(x) exp2f(x)
#endif
// exp(s/sqrt(64)) == exp2(s * 0.125 * log2(e))
#define SCLOG2E 0.18033688011118324f

#define MFMA16F(a, b, c) __builtin_amdgcn_mfma_f32_16x16x32_f16(a, b, c, 0, 0, 0)

// ---------------- projection: Y[m,n] = (f16) sum_k X[m,k]*W[n,k] + b[n] ----------------
__global__ __launch_bounds__(256) void proj_kernel2(
    const float* __restrict__ X0, const float* __restrict__ W0,
    const float* __restrict__ B0, _Float16* __restrict__ Y0,
    const float* __restrict__ X1, const float* __restrict__ W1,
    const float* __restrict__ B1, _Float16* __restrict__ Y1,
    const float* __restrict__ X2, const float* __restrict__ W2,
    const float* __restrict__ B2, _Float16* __restrict__ Y2)
{
  const int z = blockIdx.z;
  const float* X = (z == 0) ? X0 : (z == 1) ? X1 : X2;
  const float* W = (z == 0) ? W0 : (z == 1) ? W1 : W2;
  const float* Bi = (z == 0) ? B0 : (z == 1) ? B1 : B2;
  _Float16* Y = (z == 0) ? Y0 : (z == 1) ? Y1 : Y2;

  __shared__ __align__(16) float As[16][68];
  __shared__ __align__(16) float Bs[16][68];

  const int row0 = blockIdx.y * 64;
  const int col0 = blockIdx.x * 64;
  const int tn = threadIdx.x & 15;
  const int tm = threadIdx.x >> 4;
  const int srow = threadIdx.x >> 2;
  const int skq = threadIdx.x & 3;

  float acc[4][4] = {};

  for (int k0 = 0; k0 < D_MODEL; k0 += 16) {
    float4 av = *(const float4*)&X[(size_t)(row0 + srow) * D_MODEL + k0 + skq * 4];
    float4 bv = *(const float4*)&W[(size_t)(col0 + srow) * D_MODEL + k0 + skq * 4];
    __syncthreads();
    As[skq * 4 + 0][srow] = av.x; As[skq * 4 + 1][srow] = av.y;
    As[skq * 4 + 2][srow] = av.z; As[skq * 4 + 3][srow] = av.w;
    Bs[skq * 4 + 0][srow] = bv.x; Bs[skq * 4 + 1][srow] = bv.y;
    Bs[skq * 4 + 2][srow] = bv.z; Bs[skq * 4 + 3][srow] = bv.w;
    __syncthreads();
#pragma unroll
    for (int kk = 0; kk < 16; ++kk) {
      float4 a4 = *(const float4*)&As[kk][tm * 4];
      float4 b4 = *(const float4*)&Bs[kk][tn * 4];
      float a[4] = {a4.x, a4.y, a4.z, a4.w};
      float bb[4] = {b4.x, b4.y, b4.z, b4.w};
#pragma unroll
      for (int i = 0; i < 4; ++i)
#pragma unroll
        for (int j = 0; j < 4; ++j)
          acc[i][j] += a[i] * bb[j];
    }
  }
  float4 bias4 = *(const float4*)&Bi[col0 + tn * 4];
#pragma unroll
  for (int i = 0; i < 4; ++i) {
    f16x4 r;
    r[0] = (_Float16)(acc[i][0] + bias4.x);
    r[1] = (_Float16)(acc[i][1] + bias4.y);
    r[2] = (_Float16)(acc[i][2] + bias4.z);
    r[3] = (_Float16)(acc[i][3] + bias4.w);
    *(f16x4*)&Y[(size_t)(row0 + tm * 4 + i) * D_MODEL + col0 + tn * 4] = r;
  }
}

// ---------------- fused tri-einsum attention, f16 MFMA, LDS-resident K/V ----------------
__global__ __launch_bounds__(512, 1) void attn_kernel(
    const _Float16* __restrict__ Qp, const _Float16* __restrict__ Kp,
    const _Float16* __restrict__ Vp, const float* __restrict__ Ct,
    float* __restrict__ out, float* __restrict__ attn)
{
  __shared__ __align__(16) _Float16 K_lds[LB][DH];        // 32 KB
  __shared__ __align__(16) _Float16 V_lds[LB][DH];        // 32 KB
  __shared__ __align__(16) _Float16 C_lds[LC][DH + 8];    // 4.6 KB
  __shared__ __align__(16) _Float16 CT_lds[DH][LC + 8];   // 5 KB
  __shared__ __align__(16) _Float16 p_lds[2][QT * NT];    // 64 KB double-buffered
  __shared__ float red_lds[NWAVES][2][16];
  __shared__ float inv_lds[QT];

  const int tid = threadIdx.x;
  const int lane = tid & 63;
  const int w = tid >> 6;
  const int l16 = lane & 15;
  const int lg = lane >> 4;

  const int g = blockIdx.x;
  const int qt = g >> 5;          // 0..7
  const int bh = g & 31;          // same-bh blocks land on same XCD (g%8 invariant)
  const int b = bh >> 3;
  const int h = bh & 7;

  const _Float16* Kb = Kp + (size_t)b * LB * D_MODEL + h * DH;
  const _Float16* Vb = Vp + (size_t)b * LB * D_MODEL + h * DH;
  const float* Cb = Ct + (size_t)b * LC * D_MODEL + h * DH;

  // ---- one-time staging: K,V panels (32KB each), C ----
  for (int i = tid; i < (LB * DH) / 8; i += 512) {   // 4 iters/thread
    const int k = i >> 3, dg = (i & 7) * 8;
    *(f16x8*)&K_lds[k][dg] = *(const f16x8*)(Kb + (size_t)k * D_MODEL + dg);
    *(f16x8*)&V_lds[k][dg] = *(const f16x8*)(Vb + (size_t)k * D_MODEL + dg);
  }
  for (int i = tid; i < LC * DH; i += 512) {
    int c = i >> 6, d = i & 63;
    float v = Cb[(size_t)c * D_MODEL + d];
    C_lds[c][d] = (_Float16)v;
    CT_lds[d][c] = (_Float16)v;
  }

  // Q fragments: qf[nt][kh] = Q[qt*32 + nt*16 + l16][kh*32 + lg*8 .. +8]
  f16x8 qf[2][2];
  {
    const _Float16* Qbase = Qp + (size_t)(b * LA + qt * QT) * D_MODEL + h * DH;
#pragma unroll
    for (int nt = 0; nt < 2; ++nt)
#pragma unroll
      for (int kh = 0; kh < 2; ++kh)
        qf[nt][kh] = *(const f16x8*)(Qbase + (size_t)(nt * 16 + l16) * D_MODEL + kh * 32 + lg * 8);
  }
  __syncthreads();

  // s[m][nt] = S^T fragment: rows kc = kc0 + w*64 + m*16 + lg*4 + r, col q = nt*16 + l16
  auto compute_stile = [&](int kc0, f32x4 (&s)[4][2]) {
#pragma unroll
    for (int m = 0; m < 4; ++m) {
      const int kcb = kc0 + w * 64 + m * 16;
      const int k = (kcb + l16) >> 5;       // uniform across the 16-lane group
      const int c = (kcb + l16) & 31;
#pragma unroll
      for (int kh = 0; kh < 2; ++kh) {
        f16x8 kv = *(const f16x8*)&K_lds[k][kh * 32 + lg * 8];
        f16x8 cv = *(const f16x8*)&C_lds[c][kh * 32 + lg * 8];
        f16x8 af = kv * cv;                 // v_pk_mul_f16 x4
#pragma unroll
        for (int nt = 0; nt < 2; ++nt)
          s[m][nt] = MFMA16F(af, qf[nt][kh], s[m][nt]);
      }
    }
  };

  // ---- pass 1: rowsum of exp(scores) ----
  float rs0 = 0.f, rs1 = 0.f;
#pragma unroll 1
  for (int kc0 = 0; kc0 < KC_TOT; kc0 += NT) {
    f32x4 s[4][2];
#pragma unroll
    for (int m = 0; m < 4; ++m) {
      s[m][0] = (f32x4){0.f, 0.f, 0.f, 0.f};
      s[m][1] = (f32x4){0.f, 0.f, 0.f, 0.f};
    }
    compute_stile(kc0, s);
#pragma unroll
    for (int m = 0; m < 4; ++m)
#pragma unroll
      for (int r = 0; r < 4; ++r) {
        rs0 += EXP2(s[m][0][r] * SCLOG2E);
        rs1 += EXP2(s[m][1][r] * SCLOG2E);
      }
  }
  rs0 += __shfl_down(rs0, 32); rs0 += __shfl_down(rs0, 16);
  rs1 += __shfl_down(rs1, 32); rs1 += __shfl_down(rs1, 16);
  if (lane < 16) { red_lds[w][0][lane] = rs0; red_lds[w][1][lane] = rs1; }
  __syncthreads();
  if (tid < QT) {
    float t = 0.f;
    const int ntt = tid >> 4, qq = tid & 15;
#pragma unroll
    for (int ww = 0; ww < NWAVES; ++ww) t += red_lds[ww][ntt][qq];
    inv_lds[tid] = 1.f / t;
  }
  __syncthreads();
  const float inv0 = inv_lds[l16];
  const float inv1 = inv_lds[16 + l16];

  // ---- pass 2: recompute S, write attn, stage f16 p (dbuf), PV MFMA ----
  f32x4 o0 = (f32x4){0.f, 0.f, 0.f, 0.f};
  f32x4 o1 = (f32x4){0.f, 0.f, 0.f, 0.f};
  const int dbase = (w & 3) * 16;
  const int khalf = w >> 2;

#pragma unroll 1
  for (int t = 0; t < KC_TOT / NT; ++t) {
    const int kc0 = t * NT;
    char* pb = (char*)p_lds[t & 1];
    f32x4 s[4][2];
#pragma unroll
    for (int m = 0; m < 4; ++m) {
      s[m][0] = (f32x4){0.f, 0.f, 0.f, 0.f};
      s[m][1] = (f32x4){0.f, 0.f, 0.f, 0.f};
    }
    compute_stile(kc0, s);

#pragma unroll
    for (int m = 0; m < 4; ++m)
#pragma unroll
      for (int nt = 0; nt < 2; ++nt) {
        const float inv = nt ? inv1 : inv0;
        f32x4 pv;
        pv[0] = EXP2(s[m][nt][0] * SCLOG2E) * inv;
        pv[1] = EXP2(s[m][nt][1] * SCLOG2E) * inv;
        pv[2] = EXP2(s[m][nt][2] * SCLOG2E) * inv;
        pv[3] = EXP2(s[m][nt][3] * SCLOG2E) * inv;
        const int kc = kc0 + w * 64 + m * 16 + lg * 4;
        const size_t qg = (size_t)(bh * LA + qt * QT + nt * 16 + l16);
        __builtin_nontemporal_store(pv, (f32x4*)(attn + qg * KC_TOT + kc));
        const int q = nt * 16 + l16;
        f16x4 ph;
        ph[0] = (_Float16)pv[0]; ph[1] = (_Float16)pv[1];
        ph[2] = (_Float16)pv[2]; ph[3] = (_Float16)pv[3];
        const int addr = (q * (NT * 2) + (w * 64 + m * 16 + lg * 4) * 2) ^ ((q & 7) << 4);
        *(f16x4*)(pb + addr) = ph;
      }
    __syncthreads();   // single barrier: p[t&1] visible; PV(t) overlaps stile(t+1)

    // PV: waves 0-3 take kc [kc0,kc0+256), waves 4-7 take [kc0+256,kc0+512)
#pragma unroll
    for (int ks = 0; ks < 8; ++ks) {
      const int k = (kc0 >> 5) + khalf * 8 + ks;
      const _Float16 vh = V_lds[k][dbase + l16];
      f16x8 ct = *(const f16x8*)&CT_lds[dbase + l16][lg * 8];
      f16x8 af = ct * vh;
      const int kb = khalf * 512 + ks * 64 + lg * 16;
      {
        const int q = l16;
        f16x8 bfr = *(const f16x8*)(pb + ((q * (NT * 2) + kb) ^ ((q & 7) << 4)));
        o0 = MFMA16F(af, bfr, o0);
      }
      {
        const int q = 16 + l16;
        f16x8 bfr = *(const f16x8*)(pb + ((q * (NT * 2) + kb) ^ ((q & 7) << 4)));
        o1 = MFMA16F(af, bfr, o1);
      }
    }
  }
  __syncthreads();

  // cross-half reduce (waves w and w+4 computed same d-tile over disjoint kc)
  f32x4* ob = (f32x4*)p_lds[0];
  if (w >= 4) {
    ob[((w - 4) * 2 + 0) * 64 + lane] = o0;
    ob[((w - 4) * 2 + 1) * 64 + lane] = o1;
  }
  __syncthreads();
  if (w < 4) {
    o0 += ob[(w * 2 + 0) * 64 + lane];
    o1 += ob[(w * 2 + 1) * 64 + lane];
    const size_t obase = (size_t)(b * LA + qt * QT) * D_MODEL + h * DH;
#pragma unroll
    for (int r = 0; r < 4; ++r) {
      out[obase + (size_t)(l16) * D_MODEL + w * 16 + lg * 4 + r] = o0[r];
      out[obase + (size_t)(16 + l16) * D_MODEL + w * 16 + lg * 4 + r] = o1[r];
    }
  }
}

extern "C" void kernel_launch(void* const* d_in, const int* in_sizes, int n_in,
                              void* d_out, int out_size, void* d_ws, size_t ws_size,
                              hipStream_t stream) {
  const float* Q_in     = (const float*)d_in[0];
  const float* K_in     = (const float*)d_in[1];
  const float* V_in     = (const float*)d_in[2];
  const float* C_tokens = (const float*)d_in[3];
  const float* Wq       = (const float*)d_in[4];
  const float* bq       = (const float*)d_in[5];
  const float* Wk       = (const float*)d_in[6];
  const float* bk       = (const float*)d_in[7];
  const float* Wv       = (const float*)d_in[8];
  const float* bv       = (const float*)d_in[9];

  float* outp  = (float*)d_out;                           // [B,La,512]
  float* attnp = outp + (size_t)BATCH * LA * D_MODEL;     // [B,h,La,8192]

  _Float16* Qp = (_Float16*)d_ws;                         // [1024,512] f16
  _Float16* Kp = Qp + (size_t)BATCH * LA * D_MODEL;
  _Float16* Vp = Kp + (size_t)BATCH * LB * D_MODEL;

  dim3 gproj(D_MODEL / 64, (BATCH * LA) / 64, 3);
  proj_kernel2<<<gproj, 256, 0, stream>>>(Q_in, Wq, bq, Qp,
                                          K_in, Wk, bk, Kp,
                                          V_in, Wv, bv, Vp);

  attn_kernel<<<BATCH * NH * (LA / QT), 512, 0, stream>>>(Qp, Kp, Vp, C_tokens, outp, attnp);
}

// Round 7
// 124.011 us; speedup vs baseline: 1.3257x; 1.3257x over previous
//
#include <hip/hip_runtime.h>
#include <hip/hip_bf16.h>
#include <math.h>

#define D_MODEL 512
#define NH 8
#define DH 64
#define LA 256
#define LB 256
#define LC 32
#define BATCH 4
#define KC_TOT 8192

typedef float f32x4 __attribute__((ext_vector_type(4)));
typedef _Float16 f16x8 __attribute__((ext_vector_type(8)));
typedef _Float16 f16x4 __attribute__((ext_vector_type(4)));
typedef unsigned int u32;

#if __has_builtin(__builtin_amdgcn_exp2f)
#define EXP2(x) __builtin_amdgcn_exp2f(x)
#else
#define EXP2(x) exp2f(x)
#endif
// exp(s/sqrt(64)) == exp2(s * 0.125 * log2(e))
#define SCLOG2E 0.18033688011118324f

#define MFMA16F(a, b, c) __builtin_amdgcn_mfma_f32_16x16x32_f16(a, b, c, 0, 0, 0)

static __device__ __forceinline__ u32 pkrtz(float x, float y) {
  auto t = __builtin_amdgcn_cvt_pkrtz(x, y);   // __fp16 ext_vector(2)
  u32 r; __builtin_memcpy(&r, &t, 4);
  return r;
}

// ---------------- projection: Y[m,n] = (f16) sum_k X[m,k]*W[n,k] + b[n] ----------------
__global__ __launch_bounds__(256) void proj_kernel2(
    const float* __restrict__ X0, const float* __restrict__ W0,
    const float* __restrict__ B0, _Float16* __restrict__ Y0,
    const float* __restrict__ X1, const float* __restrict__ W1,
    const float* __restrict__ B1, _Float16* __restrict__ Y1,
    const float* __restrict__ X2, const float* __restrict__ W2,
    const float* __restrict__ B2, _Float16* __restrict__ Y2)
{
  const int z = blockIdx.z;
  const float* X = (z == 0) ? X0 : (z == 1) ? X1 : X2;
  const float* W = (z == 0) ? W0 : (z == 1) ? W1 : W2;
  const float* Bi = (z == 0) ? B0 : (z == 1) ? B1 : B2;
  _Float16* Y = (z == 0) ? Y0 : (z == 1) ? Y1 : Y2;

  __shared__ __align__(16) float As[16][68];
  __shared__ __align__(16) float Bs[16][68];

  const int row0 = blockIdx.y * 64;
  const int col0 = blockIdx.x * 64;
  const int tn = threadIdx.x & 15;
  const int tm = threadIdx.x >> 4;
  const int srow = threadIdx.x >> 2;
  const int skq = threadIdx.x & 3;

  float acc[4][4] = {};

  for (int k0 = 0; k0 < D_MODEL; k0 += 16) {
    float4 av = *(const float4*)&X[(size_t)(row0 + srow) * D_MODEL + k0 + skq * 4];
    float4 bv = *(const float4*)&W[(size_t)(col0 + srow) * D_MODEL + k0 + skq * 4];
    __syncthreads();
    As[skq * 4 + 0][srow] = av.x; As[skq * 4 + 1][srow] = av.y;
    As[skq * 4 + 2][srow] = av.z; As[skq * 4 + 3][srow] = av.w;
    Bs[skq * 4 + 0][srow] = bv.x; Bs[skq * 4 + 1][srow] = bv.y;
    Bs[skq * 4 + 2][srow] = bv.z; Bs[skq * 4 + 3][srow] = bv.w;
    __syncthreads();
#pragma unroll
    for (int kk = 0; kk < 16; ++kk) {
      float4 a4 = *(const float4*)&As[kk][tm * 4];
      float4 b4 = *(const float4*)&Bs[kk][tn * 4];
      float a[4] = {a4.x, a4.y, a4.z, a4.w};
      float bb[4] = {b4.x, b4.y, b4.z, b4.w};
#pragma unroll
      for (int i = 0; i < 4; ++i)
#pragma unroll
        for (int j = 0; j < 4; ++j)
          acc[i][j] += a[i] * bb[j];
    }
  }
  float4 bias4 = *(const float4*)&Bi[col0 + tn * 4];
#pragma unroll
  for (int i = 0; i < 4; ++i) {
    f16x4 r;
    r[0] = (_Float16)(acc[i][0] + bias4.x);
    r[1] = (_Float16)(acc[i][1] + bias4.y);
    r[2] = (_Float16)(acc[i][2] + bias4.z);
    r[3] = (_Float16)(acc[i][3] + bias4.w);
    *(f16x4*)&Y[(size_t)(row0 + tm * 4 + i) * D_MODEL + col0 + tn * 4] = r;
  }
}

// Block = (tile = bh*16 + qt16, half). 4 waves; wave w owns kc slice
// [half*4096 + w*1024, +1024). Scores: S^T = mfma(KC, Q) -> lane holds
// kc = base + lg*4 + r at q = l16.

// ---------------- K1: partial rowsums of exp(scores) ----------------
__global__ __launch_bounds__(256) void k1_rowsum(
    const _Float16* __restrict__ Qp, const _Float16* __restrict__ Kp,
    const float* __restrict__ Ct, float* __restrict__ ws_rs)
{
  __shared__ __align__(16) _Float16 K_lds[128][DH];      // this half's k rows
  __shared__ __align__(16) _Float16 C_lds[LC][DH + 8];
  __shared__ float red[4][16];

  const int tid = threadIdx.x;
  const int lane = tid & 63;
  const int w = tid >> 6;
  const int l16 = lane & 15;
  const int lg = lane >> 4;

  const int tile = blockIdx.x >> 1;
  const int half = blockIdx.x & 1;
  const int bh = tile >> 4;
  const int qt = tile & 15;
  const int b = bh >> 3;
  const int h = bh & 7;

  const _Float16* Kb = Kp + (size_t)b * LB * D_MODEL + h * DH;
  const float* Cb = Ct + (size_t)b * LC * D_MODEL + h * DH;

  for (int i = tid; i < 128 * DH / 8; i += 256) {
    const int k = i >> 3, dg = (i & 7) * 8;
    *(f16x8*)&K_lds[k][dg] = *(const f16x8*)(Kb + (size_t)(half * 128 + k) * D_MODEL + dg);
  }
  for (int i = tid; i < LC * DH; i += 256) {
    const int c = i >> 6, d = i & 63;
    C_lds[c][d] = (_Float16)Cb[(size_t)c * D_MODEL + d];
  }

  f16x8 qf[2];
  {
    const _Float16* Qb = Qp + (size_t)(b * LA + qt * 16) * D_MODEL + h * DH;
#pragma unroll
    for (int kh = 0; kh < 2; ++kh)
      qf[kh] = *(const f16x8*)(Qb + (size_t)l16 * D_MODEL + kh * 32 + lg * 8);
  }
  __syncthreads();

  float rs = 0.f;
#pragma unroll 2
  for (int ch = 0; ch < 32; ++ch) {
    const int krow = w * 32 + ch;
    f32x4 s0 = {0.f, 0.f, 0.f, 0.f}, s1 = {0.f, 0.f, 0.f, 0.f};
#pragma unroll
    for (int kh = 0; kh < 2; ++kh) {
      f16x8 kv = *(const f16x8*)&K_lds[krow][kh * 32 + lg * 8];
      f16x8 c0 = *(const f16x8*)&C_lds[l16][kh * 32 + lg * 8];
      f16x8 c1 = *(const f16x8*)&C_lds[16 + l16][kh * 32 + lg * 8];
      s0 = MFMA16F(kv * c0, qf[kh], s0);
      s1 = MFMA16F(kv * c1, qf[kh], s1);
    }
#pragma unroll
    for (int r = 0; r < 4; ++r)
      rs += EXP2(s0[r] * SCLOG2E) + EXP2(s1[r] * SCLOG2E);
  }
  rs += __shfl_xor(rs, 16);
  rs += __shfl_xor(rs, 32);
  if (lane < 16) red[w][lane] = rs;
  __syncthreads();
  if (tid < 16)
    ws_rs[tile * 32 + half * 16 + tid] = red[0][tid] + red[1][tid] + red[2][tid] + red[3][tid];
}

// ---------------- K2: emit normalized attn + partial PV (barrier-free hot loop) ----------------
__global__ __launch_bounds__(256) void k2_emit(
    const _Float16* __restrict__ Qp, const _Float16* __restrict__ Kp,
    const _Float16* __restrict__ Vp, const float* __restrict__ Ct,
    const float* __restrict__ ws_rs, float* __restrict__ attn,
    float* __restrict__ ws_out)
{
  __shared__ __align__(16) _Float16 K_lds[128][DH];      // 16KB (aliased as obuf later)
  __shared__ __align__(16) _Float16 C_lds[LC][DH + 8];
  __shared__ __align__(16) _Float16 CT_lds[DH][LC + 8];

  const int tid = threadIdx.x;
  const int lane = tid & 63;
  const int w = tid >> 6;
  const int l16 = lane & 15;
  const int lg = lane >> 4;

  const int tile = blockIdx.x >> 1;
  const int half = blockIdx.x & 1;
  const int bh = tile >> 4;
  const int qt = tile & 15;
  const int b = bh >> 3;
  const int h = bh & 7;

  const _Float16* Kb = Kp + (size_t)b * LB * D_MODEL + h * DH;
  const _Float16* Vb = Vp + (size_t)b * LB * D_MODEL + h * DH;
  const float* Cb = Ct + (size_t)b * LC * D_MODEL + h * DH;

  for (int i = tid; i < 128 * DH / 8; i += 256) {
    const int k = i >> 3, dg = (i & 7) * 8;
    *(f16x8*)&K_lds[k][dg] = *(const f16x8*)(Kb + (size_t)(half * 128 + k) * D_MODEL + dg);
  }
  for (int i = tid; i < LC * DH; i += 256) {
    const int c = i >> 6, d = i & 63;
    _Float16 v = (_Float16)Cb[(size_t)c * D_MODEL + d];
    C_lds[c][d] = v;
    CT_lds[d][c] = v;
  }

  f16x8 qf[2];
  {
    const _Float16* Qb = Qp + (size_t)(b * LA + qt * 16) * D_MODEL + h * DH;
#pragma unroll
    for (int kh = 0; kh < 2; ++kh)
      qf[kh] = *(const f16x8*)(Qb + (size_t)l16 * D_MODEL + kh * 32 + lg * 8);
  }
  const float inv = 1.f / (ws_rs[tile * 32 + l16] + ws_rs[tile * 32 + 16 + l16]);
  __syncthreads();

  f32x4 oacc[4] = {};
  // attn row for this lane's q, offset to this wave's kc slice
  float* arow = attn + (size_t)(bh * LA + qt * 16 + l16) * KC_TOT + half * 4096 + w * 1024;
  const int s1i = l16 + ((lg & 1) << 5);   // src lane for B-frag words 0,1
  const int s2i = s1i + 16;                // src lane for B-frag words 2,3

#pragma unroll 2
  for (int ch = 0; ch < 32; ++ch) {
    const int krow = w * 32 + ch;
    f32x4 s0 = {0.f, 0.f, 0.f, 0.f}, s1 = {0.f, 0.f, 0.f, 0.f};
#pragma unroll
    for (int kh = 0; kh < 2; ++kh) {
      f16x8 kv = *(const f16x8*)&K_lds[krow][kh * 32 + lg * 8];
      f16x8 c0 = *(const f16x8*)&C_lds[l16][kh * 32 + lg * 8];
      f16x8 c1 = *(const f16x8*)&C_lds[16 + l16][kh * 32 + lg * 8];
      s0 = MFMA16F(kv * c0, qf[kh], s0);
      s1 = MFMA16F(kv * c1, qf[kh], s1);
    }
    f32x4 p0, p1;
#pragma unroll
    for (int r = 0; r < 4; ++r) {
      p0[r] = EXP2(s0[r] * SCLOG2E) * inv;
      p1[r] = EXP2(s1[r] * SCLOG2E) * inv;
    }
    *(f32x4*)(arow + ch * 32 + lg * 4) = p0;
    *(f32x4*)(arow + ch * 32 + 16 + lg * 4) = p1;

    // p (kc at fixed q) -> PV B-fragment (q at fixed kc) via wave-local shuffles
    const u32 a0 = pkrtz(p0[0], p0[1]), a1 = pkrtz(p0[2], p0[3]);
    const u32 b0 = pkrtz(p1[0], p1[1]), b1 = pkrtz(p1[2], p1[3]);
    const u32 sa0 = (u32)__shfl((int)a0, s1i), sb0 = (u32)__shfl((int)b0, s1i);
    const u32 sa1 = (u32)__shfl((int)a1, s1i), sb1 = (u32)__shfl((int)b1, s1i);
    const u32 ta0 = (u32)__shfl((int)a0, s2i), tb0 = (u32)__shfl((int)b0, s2i);
    const u32 ta1 = (u32)__shfl((int)a1, s2i), tb1 = (u32)__shfl((int)b1, s2i);
    u32 bw[4];
    bw[0] = (lg < 2) ? sa0 : sb0;
    bw[1] = (lg < 2) ? sa1 : sb1;
    bw[2] = (lg < 2) ? ta0 : tb0;
    bw[3] = (lg < 2) ? ta1 : tb1;
    f16x8 bf; __builtin_memcpy(&bf, bw, 16);

    const _Float16* vrow = Vb + (size_t)(half * 128 + krow) * D_MODEL;
#pragma unroll
    for (int dt = 0; dt < 4; ++dt) {
      const _Float16 vv = vrow[dt * 16 + l16];
      f16x8 ct8 = *(const f16x8*)&CT_lds[dt * 16 + l16][lg * 8];
      oacc[dt] = MFMA16F(ct8 * vv, bf, oacc[dt]);
    }
  }

  // cross-wave out reduction (alias K_lds as 4096-float scratch)
  __syncthreads();
  float* obuf = (float*)&K_lds[0][0];
#pragma unroll
  for (int dt = 0; dt < 4; ++dt)
#pragma unroll
    for (int r = 0; r < 4; ++r)
      obuf[w * 1024 + l16 * 64 + dt * 16 + lg * 4 + r] = oacc[dt][r];
  __syncthreads();
  for (int e = tid; e < 1024; e += 256)
    ws_out[(size_t)(tile * 2 + half) * 1024 + e] =
        obuf[e] + obuf[1024 + e] + obuf[2048 + e] + obuf[3072 + e];
}

// ---------------- K3: reduce the two kc-half partials into out ----------------
__global__ __launch_bounds__(256) void k3_reduce(
    const float* __restrict__ ws_out, float* __restrict__ out)
{
  const int o = blockIdx.x * 256 + threadIdx.x;   // < 4*256*512
  const int col = o & 511;
  const int row = o >> 9;
  const int b = row >> 8;
  const int q = row & 255;
  const int h = col >> 6;
  const int d = col & 63;
  const int tile = (b * 8 + h) * 16 + (q >> 4);
  const float* p = ws_out + (size_t)tile * 2048 + (q & 15) * 64 + d;
  out[o] = p[0] + p[1024];
}

extern "C" void kernel_launch(void* const* d_in, const int* in_sizes, int n_in,
                              void* d_out, int out_size, void* d_ws, size_t ws_size,
                              hipStream_t stream) {
  const float* Q_in     = (const float*)d_in[0];
  const float* K_in     = (const float*)d_in[1];
  const float* V_in     = (const float*)d_in[2];
  const float* C_tokens = (const float*)d_in[3];
  const float* Wq       = (const float*)d_in[4];
  const float* bq       = (const float*)d_in[5];
  const float* Wk       = (const float*)d_in[6];
  const float* bk       = (const float*)d_in[7];
  const float* Wv       = (const float*)d_in[8];
  const float* bv       = (const float*)d_in[9];

  float* outp  = (float*)d_out;                           // [B,La,512]
  float* attnp = outp + (size_t)BATCH * LA * D_MODEL;     // [B,h,La,8192]

  _Float16* Qp = (_Float16*)d_ws;                         // [1024,512] f16
  _Float16* Kp = Qp + (size_t)BATCH * LA * D_MODEL;
  _Float16* Vp = Kp + (size_t)BATCH * LB * D_MODEL;
  float* wsf   = (float*)(Vp + (size_t)BATCH * LB * D_MODEL);
  float* ws_rs  = wsf;                                    // [512][32] f32
  float* ws_out = wsf + 512 * 32;                         // [512][2][1024] f32

  dim3 gproj(D_MODEL / 64, (BATCH * LA) / 64, 3);
  proj_kernel2<<<gproj, 256, 0, stream>>>(Q_in, Wq, bq, Qp,
                                          K_in, Wk, bk, Kp,
                                          V_in, Wv, bv, Vp);

  k1_rowsum<<<1024, 256, 0, stream>>>(Qp, Kp, C_tokens, ws_rs);
  k2_emit<<<1024, 256, 0, stream>>>(Qp, Kp, Vp, C_tokens, ws_rs, attnp, ws_out);
  k3_reduce<<<(BATCH * LA * D_MODEL) / 256, 256, 0, stream>>>(ws_out, outp);
}